// Round 15
// baseline (268.431 us; speedup 1.0000x reference)
//
#include <hip/hip_runtime.h>
#include <math.h>

#define D_MODEL 1024
#define D_INT   64
#define KW      32
#define L_SEQ   4096
#define SUBHEADS 5
#define HEADS   14
#define M_ROWS  8192
#define N_CAT   896
#define NQK     320          // SUBHEADS*64

typedef unsigned short us;
typedef unsigned int   uu;
typedef __attribute__((ext_vector_type(2))) unsigned int uu2;
typedef __attribute__((ext_vector_type(4))) unsigned int uu4;
typedef __attribute__((ext_vector_type(8))) short bf16x8_t;
typedef __attribute__((ext_vector_type(4))) float f32x4_t;

__device__ __forceinline__ float u2f(uu u) {
    float f; __builtin_memcpy(&f, &u, 4); return f;
}
__device__ __forceinline__ float blo(uu u) { return u2f(u << 16); }
__device__ __forceinline__ float bhi(uu u) { return u2f(u & 0xffff0000u); }
__device__ __forceinline__ us f2b(float f) {
    uu u; __builtin_memcpy(&u, &f, 4);
    u += 0x7fffu + ((u >> 16) & 1u);
    return (us)(u >> 16);
}
__device__ __forceinline__ uu pack2(float a, float b) {
    return (uu)f2b(a) | ((uu)f2b(b) << 16);
}
// hardware packed cvt: RNE, bit-identical to pack2
__device__ __forceinline__ uu cvtpk(float a, float b) {
    uu r;
    asm("v_cvt_pk_bf16_f32 %0, %1, %2" : "=v"(r) : "v"(a), "v"(b));
    return r;
}
__device__ __forceinline__ void load16(void* lds, const void* g) {
    __builtin_amdgcn_global_load_lds(
        (const __attribute__((address_space(1))) unsigned int*)g,
        (__attribute__((address_space(3))) unsigned int*)lds, 16, 0, 0);
}
__device__ __forceinline__ int subhead_of(int h) {
    return (h < 5) ? 0 : (h < 10) ? 1 : (h < 12) ? 2 : (h == 12) ? 3 : 4;
}

// ---------------------------------------------------------------------------
// Prep mega-kernel (round-10 proven: ILP-forced casts + transpose-casts).
// ---------------------------------------------------------------------------
#define CAST_BLK 3072
__global__ __launch_bounds__(256)
void prep_kernel(const float* __restrict__ q, const float* __restrict__ k,
                 const float* __restrict__ v,
                 const float* __restrict__ Wq, const float* __restrict__ Wk,
                 const float* __restrict__ Wv, const float* __restrict__ Wc,
                 us* __restrict__ Xq, us* __restrict__ Xk, us* __restrict__ Xv,
                 us* __restrict__ Wqt, us* __restrict__ Wkt,
                 us* __restrict__ Wvt, us* __restrict__ Wct)
{
    __shared__ float t[32][33];
    const int tid = threadIdx.x;
    const int b = blockIdx.x;

    if (b < CAST_BLK) {
        const int arr = b >> 10;              // 0,1,2
        const int blk = b & 1023;
        const f32x4_t* s = (const f32x4_t*)((arr == 0) ? q : (arr == 1) ? k : v);
        uu2* d = (uu2*)((arr == 0) ? Xq : (arr == 1) ? Xk : Xv);
        const int i0 = blk * 2048 + tid;      // block covers 2048 float4
        f32x4_t xs[8];
#pragma unroll
        for (int kk = 0; kk < 8; kk++)
            xs[kk] = __builtin_nontemporal_load(&s[i0 + kk * 256]);
#pragma unroll
        for (int kk = 0; kk < 8; kk++) {
            uu2 o;
            o.x = cvtpk(xs[kk].x, xs[kk].y);
            o.y = cvtpk(xs[kk].z, xs[kk].w);
            d[i0 + kk * 256] = o;
        }
        return;
    }

    int g = b - CAST_BLK;
    const float* S; us* D; int K, N;
    if (g < 640) {
        if (g < 320) { S = Wq; D = Wqt; } else { S = Wk; D = Wkt; g -= 320; }
        K = 1024; N = 64;
    } else if (g < 1536) {
        g -= 640; S = Wv; D = Wvt; K = 1024; N = 64;
    } else {
        g -= 1536; S = Wc; D = Wct; K = 896; N = 1024;
    }
    const int nkx = K >> 5;
    const int kx = g % nkx;
    const int rest = g / nkx;
    const int ny = rest % (N >> 5);
    const int z  = rest / (N >> 5);
    const int k0 = kx * 32, n0 = ny * 32;
    S += (size_t)z * K * N;
    D += (size_t)z * K * N;
    const int tx = tid & 31, ty = tid >> 5;
#pragma unroll
    for (int r = 0; r < 32; r += 8)
        t[r + ty][tx] = __builtin_nontemporal_load(&S[(size_t)(k0 + r + ty) * N + n0 + tx]);
    __syncthreads();
#pragma unroll
    for (int r = 0; r < 32; r += 8)
        D[(size_t)(n0 + r + ty) * K + k0 + tx] = f2b(t[tx][r + ty]);
}

// ---------------------------------------------------------------------------
// 128x64-tile GEMM core, 8 waves (512 thr). Wave tile 32x32, acc[2][2].
// qk remainder only.
// ---------------------------------------------------------------------------
__device__ __forceinline__
void gemm64_core(const us* __restrict__ A, const us* __restrict__ Bt,
                 const float* __restrict__ bias, us* __restrict__ C,
                 int K, int ldC, int row0, int col0, us* As, us* Bs)
{
    const int tid = threadIdx.x, w = tid >> 6, lane = tid & 63;
    const int m = lane & 15, quad = lane >> 4;
    const int sr = lane >> 3;
    const int scs = (lane & 7) ^ sr;
    const int mrow0 = (w & 3) * 32, ncol0 = (w >> 2) * 32;

    f32x4_t z4 = {0.f, 0.f, 0.f, 0.f};
    f32x4_t acc[2][2] = {{z4, z4}, {z4, z4}};

    for (int k0 = 0; k0 < K; k0 += 64) {
#pragma unroll
        for (int p = 0; p < 2; p++) {
            const int r = w * 16 + p * 8 + sr;
            load16(&As[(w * 16 + p * 8) * 64], A + (size_t)(row0 + r) * K + k0 + scs * 8);
        }
        {
            const int r = w * 8 + sr;
            load16(&Bs[(w * 8) * 64], Bt + (size_t)(col0 + r) * K + k0 + scs * 8);
        }
        __syncthreads();
#pragma unroll
        for (int ks = 0; ks < 2; ks++) {
            const int slot = ((ks * 4 + quad) ^ (m & 7)) * 8;
            bf16x8_t a[2], b[2];
#pragma unroll
            for (int t = 0; t < 2; t++) {
                a[t] = *(const bf16x8_t*)&As[(mrow0 + t * 16 + m) * 64 + slot];
                b[t] = *(const bf16x8_t*)&Bs[(ncol0 + t * 16 + m) * 64 + slot];
            }
#pragma unroll
            for (int i = 0; i < 2; i++)
#pragma unroll
                for (int j = 0; j < 2; j++)
                    acc[i][j] = __builtin_amdgcn_mfma_f32_16x16x32_bf16(a[i], b[j], acc[i][j], 0, 0, 0);
        }
        __syncthreads();
    }

#pragma unroll
    for (int i = 0; i < 2; i++) {
        const int rbase = row0 + mrow0 + i * 16 + quad * 4;
#pragma unroll
        for (int j = 0; j < 2; j++) {
            const int col = col0 + ncol0 + j * 16 + m;
            const float bi = bias[col];
#pragma unroll
            for (int r = 0; r < 4; r++)
                C[(size_t)(rbase + r) * ldC + col] = f2b(acc[i][j][r] + bi);
        }
    }
}

// ---------------------------------------------------------------------------
// 128x128-tile core, 8 waves (512 thr), wave tile 64x32, acc[4][2]
// — the round-10 measured-best config. 32 KB LDS.
// ---------------------------------------------------------------------------
__device__ __forceinline__
void gemm128_core(const us* __restrict__ A, const us* __restrict__ Bt,
                  const float* __restrict__ bias, void* __restrict__ Cv,
                  int K, int ldC, int outBf16, int row0, int col0,
                  us* As, us* Bs)
{
    const int tid = threadIdx.x, w = tid >> 6, lane = tid & 63;
    const int m = lane & 15, quad = lane >> 4;
    const int sr = lane >> 3;
    const int scs = (lane & 7) ^ sr;
    const int mrow0 = (w & 1) * 64, ncol0 = (w >> 1) * 32;

    f32x4_t z = {0.f, 0.f, 0.f, 0.f};
    f32x4_t acc[4][2] = {{z,z},{z,z},{z,z},{z,z}};

    for (int k0 = 0; k0 < K; k0 += 64) {
#pragma unroll
        for (int p = 0; p < 2; p++) {
            const int r = w * 16 + p * 8 + sr;
            load16(&As[(w * 16 + p * 8) * 64], A  + (size_t)(row0 + r) * K + k0 + scs * 8);
            load16(&Bs[(w * 16 + p * 8) * 64], Bt + (size_t)(col0 + r) * K + k0 + scs * 8);
        }
        __syncthreads();
#pragma unroll
        for (int ks = 0; ks < 2; ks++) {
            const int slot = ((ks * 4 + quad) ^ (m & 7)) * 8;
            bf16x8_t a[4], b[2];
#pragma unroll
            for (int t = 0; t < 4; t++)
                a[t] = *(const bf16x8_t*)&As[(mrow0 + t * 16 + m) * 64 + slot];
#pragma unroll
            for (int t = 0; t < 2; t++)
                b[t] = *(const bf16x8_t*)&Bs[(ncol0 + t * 16 + m) * 64 + slot];
#pragma unroll
            for (int i = 0; i < 4; i++)
#pragma unroll
                for (int j = 0; j < 2; j++)
                    acc[i][j] = __builtin_amdgcn_mfma_f32_16x16x32_bf16(a[i], b[j], acc[i][j], 0, 0, 0);
        }
        __syncthreads();
    }

#pragma unroll
    for (int i = 0; i < 4; i++) {
        const int rbase = row0 + mrow0 + i * 16 + quad * 4;
        if (outBf16) {
            us* Cb = (us*)Cv;
#pragma unroll
            for (int j = 0; j < 2; j++) {
                const int col = col0 + ncol0 + j * 16 + m;
                const float bi = bias[col];
#pragma unroll
                for (int r = 0; r < 4; r++)
                    Cb[(size_t)(rbase + r) * ldC + col] = f2b(acc[i][j][r] + bi);
            }
        } else {
            float* Cb = (float*)Cv;
#pragma unroll
            for (int j = 0; j < 2; j++) {
                const int col = col0 + ncol0 + j * 16 + m;
                const float bi = bias[col];
#pragma unroll
                for (int r = 0; r < 4; r++)
                    Cb[(size_t)(rbase + r) * ldC + col] = acc[i][j][r] + bi;
            }
        }
    }
}

// ---------------------------------------------------------------------------
// Fused projections (512 threads/block), round-10 layout:
//   blocks [0,448):   v 128x128 (64 x 7)
//   blocks [448,704): q/k cols 0-255 as 128x128 (64 x 2 x {q,k})
//   blocks [704,832): q/k cols 256-319 remainder as 128x64 (64 x {q,k})
// ---------------------------------------------------------------------------
__global__ __launch_bounds__(512)
void proj_kernel(const us* __restrict__ Xq, const us* __restrict__ Xk,
                 const us* __restrict__ Xv,
                 const us* __restrict__ Wqt, const us* __restrict__ Wkt,
                 const us* __restrict__ Wvt,
                 const float* __restrict__ bq, const float* __restrict__ bk,
                 const float* __restrict__ bv,
                 us* __restrict__ qbuf, us* __restrict__ kbuf,
                 us* __restrict__ vbuf)
{
    __shared__ us As[128 * 64];
    __shared__ us Bs[128 * 64];
    const int b = blockIdx.x;
    if (b < 448) {
        gemm128_core(Xv, Wvt, bv, vbuf, D_MODEL, N_CAT, 1,
                     (b & 63) << 7, (b >> 6) << 7, As, Bs);
    } else if (b < 704) {
        const int idx = b - 448;
        const int bx = idx & 63;
        const int rest = idx >> 6;                   // 0..3
        const int cy = rest & 1, z = rest >> 1;
        gemm128_core(z ? Xk : Xq, z ? Wkt : Wqt, z ? bk : bq,
                     z ? kbuf : qbuf, D_MODEL, NQK, 1,
                     bx << 7, cy << 7, As, Bs);
    } else {
        const int idx = b - 704;
        const int bx = idx & 63;
        const int z  = idx >> 6;                     // 0,1
        gemm64_core(z ? Xk : Xq, z ? Wkt : Wqt, z ? bk : bq,
                    z ? kbuf : qbuf, D_MODEL, NQK,
                    bx << 7, 256, As, Bs);
    }
}

// out gemm: [8192][896] bf16 @ [896][1024] -> fp32 (round-10 proven config)
__global__ __launch_bounds__(512)
void gemm_out(const us* __restrict__ ab, const us* __restrict__ Wct,
              const float* __restrict__ bc, float* __restrict__ out)
{
    __shared__ us As[128 * 64];
    __shared__ us Bs[128 * 64];
    gemm128_core(ab, Wct, bc, out, N_CAT, D_MODEL, 0,
                 (int)(blockIdx.x << 7), (int)(blockIdx.y << 7), As, Bs);
}

// ---------------------------------------------------------------------------
// d=1 attention kernel (heads 0-9): MFMA scores (round-13 proven).
// ---------------------------------------------------------------------------
__global__ __launch_bounds__(256)
void attn_d1_kernel(const us* __restrict__ qb, const us* __restrict__ kb,
                    const us* __restrict__ vb,
                    const float* __restrict__ Ws, const float* __restrict__ bs,
                    us* __restrict__ ab)
{
    __shared__ us kq[96 * 64 + 64 * 64];   // Ks [96][64] | Qs [64][64]
    __shared__ float sab[64 * 36];

    us* Ks = kq;
    us* Qs = kq + 96 * 64;
    uu* vslab = (uu*)kq;                   // [95][36] aliases Ks/Qs (PV phase)

    const int tid  = threadIdx.x;
    const int wave = tid >> 6;
    const int lane = tid & 63;
    const int m    = lane & 15, quad = lane >> 4;
    const int sr   = lane >> 3;
    const int scs  = (lane & 7) ^ sr;
    const int j32  = lane & 31;
    const int half = lane >> 5;
    const int h    = blockIdx.y;           // 0..9
    const int s    = (h < 5) ? 0 : 1;
    const int ml0  = blockIdx.x * 64;
    const int l0   = ml0 & 4095;
    const int bm   = ml0 - l0;

    // ---- stage K (96 rows, window l0-16..l0+79) + Q (64 rows), swizzled ----
#pragma unroll
    for (int call = 0; call < 3; call++) {
        const int g = call * 4 + wave;       // 0..11
        const int r = g * 8 + sr;            // 0..95
        int src = l0 - 16 + r;
        src = src < 0 ? 0 : (src > 4095 ? 4095 : src);
        load16(&Ks[(g * 8) * 64], kb + (size_t)(bm + src) * NQK + s * 64 + scs * 8);
    }
#pragma unroll
    for (int call = 0; call < 2; call++) {
        const int g = call * 4 + wave;       // 0..7
        const int r = g * 8 + sr;            // 0..63
        load16(&Qs[(g * 8) * 64], qb + (size_t)(ml0 + r) * NQK + s * 64 + scs * 8);
    }

    // ---- T14: issue v loads now (drained by barrier-1) ----
    const uu4* vg4 = (const uu4*)vb;       // row stride 112 uu4
    uu4 vreg[3];
#pragma unroll
    for (int it = 0; it < 3; it++) {
        const int idx = it * 256 + tid;
        if (idx < 95 * 8) {
            const int r = idx >> 3, c4 = idx & 7;
            int src = l0 - 16 + r;
            src = src < 0 ? 0 : (src > 4095 ? 4095 : src);
            vreg[it] = vg4[(size_t)(bm + src) * 112 + h * 8 + c4];
        }
    }
    __syncthreads();

    // ---- scores via MFMA: wave p-tile p0, 3 w-tiles, K=64 (2 steps) ----
    const int p0 = wave * 16;
    f32x4_t z = {0.f, 0.f, 0.f, 0.f};
    f32x4_t accs[3] = {z, z, z};
#pragma unroll
    for (int ks = 0; ks < 2; ks++) {
        const int slot = ((ks * 4 + quad) ^ (m & 7)) * 8;
        bf16x8_t qa = *(const bf16x8_t*)&Qs[(p0 + m) * 64 + slot];
#pragma unroll
        for (int wt = 0; wt < 3; wt++) {
            bf16x8_t kb8 = *(const bf16x8_t*)&Ks[(p0 + wt * 16 + m) * 64 + slot];
            accs[wt] = __builtin_amdgcn_mfma_f32_16x16x32_bf16(qa, kb8, accs[wt], 0, 0, 0);
        }
    }
    // banded extract -> sab (C layout: row = quad*4+reg, col = m)
#pragma unroll
    for (int wt = 0; wt < 3; wt++)
#pragma unroll
        for (int r = 0; r < 4; r++) {
            const int ploc = quad * 4 + r;
            const int j = wt * 16 + m - ploc;
            if (j >= 0 && j < 32)
                sab[(p0 + ploc) * 36 + j] = accs[wt][r] * 0.125f;
        }
    __syncthreads();    // Ks/Qs reads done -> vslab overwrite safe

    // ---- v ds_writes from registers ----
#pragma unroll
    for (int it = 0; it < 3; it++) {
        const int idx = it * 256 + tid;
        if (idx < 95 * 8) {
            const int r = idx >> 3, c4 = idx & 7;
            *(uu4*)&vslab[r * 36 + c4 * 4] = vreg[it];
        }
    }
    float wsr[32];
#pragma unroll
    for (int k = 0; k < 32; k++) wsr[k] = Ws[(size_t)h * 1024 + k * 32 + j32];
    const float bsv = bs[h * 32 + j32];

    // ---- resample + softmax -> sab overwrite (wave-private rows) ----
#pragma unroll
    for (int i = 0; i < 8; i++) {
        const int p = wave * 16 + i * 2 + half;
        const float4* s4 = (const float4*)&sab[p * 36];
        float acc = bsv;
#pragma unroll
        for (int q = 0; q < 8; q++) {
            float4 v = s4[q];
            acc = fmaf(v.x, wsr[q * 4 + 0], acc);
            acc = fmaf(v.y, wsr[q * 4 + 1], acc);
            acc = fmaf(v.z, wsr[q * 4 + 2], acc);
            acc = fmaf(v.w, wsr[q * 4 + 3], acc);
        }
        float mx = acc;
#pragma unroll
        for (int off = 16; off > 0; off >>= 1) mx = fmaxf(mx, __shfl_xor(mx, off, 64));
        float ex = __expf(acc - mx);
        float sum = ex;
#pragma unroll
        for (int off = 16; off > 0; off >>= 1) sum += __shfl_xor(sum, off, 64);
        sab[p * 36 + j32] = ex / sum;
    }
    __syncthreads();   // vslab fully staged

    // ---- PV: 8 positions per pass (d=1: row base = p) ----
    const int o = lane >> 3;
    const int c = lane & 7;
#pragma unroll
    for (int pass = 0; pass < 2; pass++) {
        const int p  = wave * 16 + pass * 8 + o;
        const int ml = ml0 + p;
        float a0 = 0.f, a1 = 0.f, a2 = 0.f, a3 = 0.f;
        float a4 = 0.f, a5 = 0.f, a6 = 0.f, a7 = 0.f;
#pragma unroll
        for (int mg = 0; mg < 4; mg++) {
            const float4 wA = *(const float4*)&sab[p * 36 + mg * 8];
            const float4 wB = *(const float4*)&sab[p * 36 + mg * 8 + 4];
            const float at8[8] = {wA.x, wA.y, wA.z, wA.w, wB.x, wB.y, wB.z, wB.w};
#pragma unroll
            for (int m2 = 0; m2 < 8; m2++) {
                const float at = at8[m2];
                uu4 vd = *(const uu4*)&vslab[(p + mg * 8 + m2) * 36 + c * 4];
                a0 = fmaf(blo(vd.x), at, a0); a1 = fmaf(bhi(vd.x), at, a1);
                a2 = fmaf(blo(vd.y), at, a2); a3 = fmaf(bhi(vd.y), at, a3);
                a4 = fmaf(blo(vd.z), at, a4); a5 = fmaf(bhi(vd.z), at, a5);
                a6 = fmaf(blo(vd.w), at, a6); a7 = fmaf(bhi(vd.w), at, a7);
            }
        }
        uu4 od;
        od.x = pack2(a0, a1); od.y = pack2(a2, a3);
        od.z = pack2(a4, a5); od.w = pack2(a6, a7);
        *(uu4*)&((uu*)ab)[(size_t)ml * 448 + h * 32 + c * 4] = od;
    }
}

// ---------------------------------------------------------------------------
// Dilated attention kernel (heads 10-13, scalar path). NOW SPLIT:
//   <126> for heads 10-11 (d=2, W=126): 34.7 KB LDS -> 4 blocks/CU
//   <312> for heads 12-13 (d=4/8):      62.3 KB LDS -> 2 blocks/CU
// ---------------------------------------------------------------------------
template<int ROWS>
__global__ __launch_bounds__(256)
void attn_kernel(const us* __restrict__ qb, const us* __restrict__ kb,
                 const us* __restrict__ vb,
                 const float* __restrict__ Ws, const float* __restrict__ bs,
                 us* __restrict__ ab, int hbase)
{
    __shared__ uu    kv[ROWS * 36];
    __shared__ uu    qslab[64 * 32];
    __shared__ float sab[64 * 36];

    constexpr int VT = (ROWS * 8 + 255) / 256;

    const int tid  = threadIdx.x;
    const int wave = tid >> 6;
    const int lane = tid & 63;
    const int j    = lane & 31;
    const int half = lane >> 5;
    const int h    = hbase + blockIdx.y;
    const int s    = subhead_of(h);
    const int ld   = (s <= 1) ? 0 : (s - 1);
    const int d    = 1 << ld;
    const int ml0  = blockIdx.x * 64;
    const int l0   = ml0 & 4095;
    const int bm   = ml0 - l0;
    const int W    = 64 + 31 * d;
    const int Bseg = W >> ld;

    const uu4* kg4 = (const uu4*)kb;
    const uu4* qg4 = (const uu4*)qb;
    for (int idx = tid; idx < W * 8; idx += 256) {
        int r = idx >> 3, c4 = idx & 7;
        int src = l0 - 16 * d + r;
        src = src < 0 ? 0 : (src > 4095 ? 4095 : src);
        int slot = (r & (d - 1)) * Bseg + (r >> ld);
        *(uu4*)&kv[slot * 36 + c4 * 4] = kg4[(size_t)(bm + src) * 40 + s * 8 + c4];
    }
#pragma unroll
    for (int it = 0; it < 2; it++) {
        const int idx = it * 256 + tid;
        const int r = idx >> 3, c4 = idx & 7;
        load16(&qslab[(it * 256 + wave * 64) * 4],
               &qg4[(size_t)(ml0 + r) * 40 + s * 8 + c4]);
    }

    const uu4* vg4 = (const uu4*)vb;
    uu4 vreg[VT];
#pragma unroll
    for (int it = 0; it < VT; it++) {
        const int idx = it * 256 + tid;
        if (idx < W * 8) {
            const int r = idx >> 3, c4 = idx & 7;
            int src = l0 - 16 * d + r;
            src = src < 0 ? 0 : (src > 4095 ? 4095 : src);
            vreg[it] = vg4[(size_t)(bm + src) * 112 + h * 8 + c4];
        }
    }
    __syncthreads();

#pragma unroll
    for (int i = 0; i < 8; i++) {
        const int p = wave * 16 + i * 2 + half;
        const int sb = (p & (d - 1)) * Bseg + (p >> ld);
        const uu4* k4 = (const uu4*)&kv[(sb + j) * 36];
        const uu4* q4 = (const uu4*)&qslab[p * 32];
        float acc = 0.f;
#pragma unroll
        for (int q = 0; q < 8; q++) {
            uu4 kd = k4[q];
            uu4 qd = q4[q];
            acc = fmaf(blo(kd.x), blo(qd.x), acc); acc = fmaf(bhi(kd.x), bhi(qd.x), acc);
            acc = fmaf(blo(kd.y), blo(qd.y), acc); acc = fmaf(bhi(kd.y), bhi(qd.y), acc);
            acc = fmaf(blo(kd.z), blo(qd.z), acc); acc = fmaf(bhi(kd.z), bhi(qd.z), acc);
            acc = fmaf(blo(kd.w), blo(qd.w), acc); acc = fmaf(bhi(kd.w), bhi(qd.w), acc);
        }
        sab[p * 36 + j] = acc * 0.125f;
    }
    __syncthreads();

#pragma unroll
    for (int it = 0; it < VT; it++) {
        const int idx = it * 256 + tid;
        if (idx < W * 8) {
            const int r = idx >> 3, c4 = idx & 7;
            const int slot = (r & (d - 1)) * Bseg + (r >> ld);
            *(uu4*)&kv[slot * 36 + c4 * 4] = vreg[it];
        }
    }
    float wsr[32];
#pragma unroll
    for (int k = 0; k < 32; k++) wsr[k] = Ws[(size_t)h * 1024 + k * 32 + j];
    const float bsv = bs[h * 32 + j];

#pragma unroll
    for (int i = 0; i < 8; i++) {
        const int p = wave * 16 + i * 2 + half;
        const float4* s4 = (const float4*)&sab[p * 36];
        float acc = bsv;
#pragma unroll
        for (int q = 0; q < 8; q++) {
            float4 v = s4[q];
            acc = fmaf(v.x, wsr[q * 4 + 0], acc);
            acc = fmaf(v.y, wsr[q * 4 + 1], acc);
            acc = fmaf(v.z, wsr[q * 4 + 2], acc);
            acc = fmaf(v.w, wsr[q * 4 + 3], acc);
        }
        float mx = acc;
#pragma unroll
        for (int off = 16; off > 0; off >>= 1) mx = fmaxf(mx, __shfl_xor(mx, off, 64));
        float ex = __expf(acc - mx);
        float sum = ex;
#pragma unroll
        for (int off = 16; off > 0; off >>= 1) sum += __shfl_xor(sum, off, 64);
        sab[p * 36 + j] = ex / sum;
    }
    __syncthreads();

    const int o = lane >> 3;
    const int c = lane & 7;
#pragma unroll
    for (int pass = 0; pass < 2; pass++) {
        const int p  = wave * 16 + pass * 8 + o;
        const int ml = ml0 + p;
        const int sbp = (p & (d - 1)) * Bseg + (p >> ld);
        float a0 = 0.f, a1 = 0.f, a2 = 0.f, a3 = 0.f;
        float a4 = 0.f, a5 = 0.f, a6 = 0.f, a7 = 0.f;
#pragma unroll
        for (int mg = 0; mg < 4; mg++) {
            const float4 wA = *(const float4*)&sab[p * 36 + mg * 8];
            const float4 wB = *(const float4*)&sab[p * 36 + mg * 8 + 4];
            const float at8[8] = {wA.x, wA.y, wA.z, wA.w, wB.x, wB.y, wB.z, wB.w};
#pragma unroll
            for (int m2 = 0; m2 < 8; m2++) {
                const float at = at8[m2];
                uu4 vd = *(const uu4*)&kv[(sbp + mg * 8 + m2) * 36 + c * 4];
                a0 = fmaf(blo(vd.x), at, a0); a1 = fmaf(bhi(vd.x), at, a1);
                a2 = fmaf(blo(vd.y), at, a2); a3 = fmaf(bhi(vd.y), at, a3);
                a4 = fmaf(blo(vd.z), at, a4); a5 = fmaf(bhi(vd.z), at, a5);
                a6 = fmaf(blo(vd.w), at, a6); a7 = fmaf(bhi(vd.w), at, a7);
            }
        }
        uu4 od;
        od.x = pack2(a0, a1); od.y = pack2(a2, a3);
        od.z = pack2(a4, a5); od.w = pack2(a6, a7);
        *(uu4*)&((uu*)ab)[(size_t)ml * 448 + h * 32 + c * 4] = od;
    }
}

// ---------------------------------------------------------------------------
extern "C" void kernel_launch(void* const* d_in, const int* in_sizes, int n_in,
                              void* d_out, int out_size, void* d_ws, size_t ws_size,
                              hipStream_t stream)
{
    const float* query = (const float*)d_in[0];
    const float* key   = (const float*)d_in[1];
    const float* value = (const float*)d_in[2];
    const float* Wq    = (const float*)d_in[3];
    const float* bq    = (const float*)d_in[4];
    const float* Wk    = (const float*)d_in[5];
    const float* bk    = (const float*)d_in[6];
    const float* Wv    = (const float*)d_in[7];
    const float* bv    = (const float*)d_in[8];
    const float* Ws    = (const float*)d_in[9];
    const float* bs    = (const float*)d_in[10];
    const float* Wc    = (const float*)d_in[11];
    const float* bc    = (const float*)d_in[12];
    float* out = (float*)d_out;

    // workspace carve (bf16 elements). ab aliases Xq (Xq dead after q gemm).
    us* w = (us*)d_ws;
    us* Xq  = w;                          // 8192*1024
    us* ab  = w;                          // 8192*896 (alias of Xq)
    us* Xk  = Xq  + (size_t)M_ROWS * D_MODEL;
    us* Xv  = Xk  + (size_t)M_ROWS * D_MODEL;
    us* Wqt = Xv  + (size_t)M_ROWS * D_MODEL;           // [320][1024]
    us* Wkt = Wqt + (size_t)SUBHEADS * D_INT * D_MODEL;
    us* Wvt = Wkt + (size_t)SUBHEADS * D_INT * D_MODEL; // [896][1024]
    us* Wct = Wvt + (size_t)HEADS * D_INT * D_MODEL;    // [1024][896]
    us* qbuf = Wct + (size_t)D_MODEL * N_CAT;           // [8192][320]
    us* kbuf = qbuf + (size_t)M_ROWS * NQK;
    us* vbuf = kbuf + (size_t)M_ROWS * NQK;             // [8192][896]

    dim3 blk(256);
    dim3 blk512(512);

    // prep: ILP-forced q/k/v casts + weight transposes in one launch
    prep_kernel<<<dim3(CAST_BLK + 2432), blk, 0, stream>>>(
        query, key, value,
        Wq, Wk, Wv, Wc, Xq, Xk, Xv, Wqt, Wkt, Wvt, Wct);

    // fused q/k/v projections: 448 v-128 + 256 qk-128 + 128 qk-64 = 832
    proj_kernel<<<dim3(832), blk512, 0, stream>>>(
        Xq, Xk, Xv, Wqt, Wkt, Wvt, bq, bk, bv, qbuf, kbuf, vbuf);

    // attention:
    //   heads 0-9 (d=1): MFMA-scores kernel, grid 1280, 29.7 KB -> 5/CU
    //   heads 10-11 (d=2, W=126): <126>, 34.7 KB -> 4/CU
    //   heads 12-13 (d=4/8, W<=312): <312>, 62.3 KB -> 2/CU
    attn_d1_kernel<<<dim3(M_ROWS / 64, 10), blk, 0, stream>>>(
        qbuf, kbuf, vbuf, Ws, bs, ab);
    attn_kernel<126><<<dim3(M_ROWS / 64, 2), blk, 0, stream>>>(
        qbuf, kbuf, vbuf, Ws, bs, ab, 10);
    attn_kernel<312><<<dim3(M_ROWS / 64, 2), blk, 0, stream>>>(
        qbuf, kbuf, vbuf, Ws, bs, ab, 12);

    // out gemm: [8192][896] @ [896][1024] -> fp32 (round-10 config)
    gemm_out<<<dim3(M_ROWS / 128, D_MODEL / 128), blk512, 0, stream>>>(
        ab, Wct, bc, out);
}

// Round 16
// 253.642 us; speedup vs baseline: 1.0583x; 1.0583x over previous
//
#include <hip/hip_runtime.h>
#include <math.h>

#define D_MODEL 1024
#define D_INT   64
#define KW      32
#define L_SEQ   4096
#define SUBHEADS 5
#define HEADS   14
#define M_ROWS  8192
#define N_CAT   896
#define NQK     320          // SUBHEADS*64

typedef unsigned short us;
typedef unsigned int   uu;
typedef __attribute__((ext_vector_type(2))) unsigned int uu2;
typedef __attribute__((ext_vector_type(4))) unsigned int uu4;
typedef __attribute__((ext_vector_type(8))) short bf16x8_t;
typedef __attribute__((ext_vector_type(4))) float f32x4_t;

__device__ __forceinline__ float u2f(uu u) {
    float f; __builtin_memcpy(&f, &u, 4); return f;
}
__device__ __forceinline__ float blo(uu u) { return u2f(u << 16); }
__device__ __forceinline__ float bhi(uu u) { return u2f(u & 0xffff0000u); }
__device__ __forceinline__ us f2b(float f) {
    uu u; __builtin_memcpy(&u, &f, 4);
    u += 0x7fffu + ((u >> 16) & 1u);
    return (us)(u >> 16);
}
__device__ __forceinline__ uu pack2(float a, float b) {
    return (uu)f2b(a) | ((uu)f2b(b) << 16);
}
// hardware packed cvt: RNE, bit-identical to pack2
__device__ __forceinline__ uu cvtpk(float a, float b) {
    uu r;
    asm("v_cvt_pk_bf16_f32 %0, %1, %2" : "=v"(r) : "v"(a), "v"(b));
    return r;
}
__device__ __forceinline__ void load16(void* lds, const void* g) {
    __builtin_amdgcn_global_load_lds(
        (const __attribute__((address_space(1))) unsigned int*)g,
        (__attribute__((address_space(3))) unsigned int*)lds, 16, 0, 0);
}
__device__ __forceinline__ int subhead_of(int h) {
    return (h < 5) ? 0 : (h < 10) ? 1 : (h < 12) ? 2 : (h == 12) ? 3 : 4;
}

// ---------------------------------------------------------------------------
// Prep mega-kernel (round-10 proven: ILP-forced casts + transpose-casts).
// ---------------------------------------------------------------------------
#define CAST_BLK 3072
__global__ __launch_bounds__(256)
void prep_kernel(const float* __restrict__ q, const float* __restrict__ k,
                 const float* __restrict__ v,
                 const float* __restrict__ Wq, const float* __restrict__ Wk,
                 const float* __restrict__ Wv, const float* __restrict__ Wc,
                 us* __restrict__ Xq, us* __restrict__ Xk, us* __restrict__ Xv,
                 us* __restrict__ Wqt, us* __restrict__ Wkt,
                 us* __restrict__ Wvt, us* __restrict__ Wct)
{
    __shared__ float t[32][33];
    const int tid = threadIdx.x;
    const int b = blockIdx.x;

    if (b < CAST_BLK) {
        const int arr = b >> 10;              // 0,1,2
        const int blk = b & 1023;
        const f32x4_t* s = (const f32x4_t*)((arr == 0) ? q : (arr == 1) ? k : v);
        uu2* d = (uu2*)((arr == 0) ? Xq : (arr == 1) ? Xk : Xv);
        const int i0 = blk * 2048 + tid;      // block covers 2048 float4
        f32x4_t xs[8];
#pragma unroll
        for (int kk = 0; kk < 8; kk++)
            xs[kk] = __builtin_nontemporal_load(&s[i0 + kk * 256]);
#pragma unroll
        for (int kk = 0; kk < 8; kk++) {
            uu2 o;
            o.x = cvtpk(xs[kk].x, xs[kk].y);
            o.y = cvtpk(xs[kk].z, xs[kk].w);
            d[i0 + kk * 256] = o;
        }
        return;
    }

    int g = b - CAST_BLK;
    const float* S; us* D; int K, N;
    if (g < 640) {
        if (g < 320) { S = Wq; D = Wqt; } else { S = Wk; D = Wkt; g -= 320; }
        K = 1024; N = 64;
    } else if (g < 1536) {
        g -= 640; S = Wv; D = Wvt; K = 1024; N = 64;
    } else {
        g -= 1536; S = Wc; D = Wct; K = 896; N = 1024;
    }
    const int nkx = K >> 5;
    const int kx = g % nkx;
    const int rest = g / nkx;
    const int ny = rest % (N >> 5);
    const int z  = rest / (N >> 5);
    const int k0 = kx * 32, n0 = ny * 32;
    S += (size_t)z * K * N;
    D += (size_t)z * K * N;
    const int tx = tid & 31, ty = tid >> 5;
#pragma unroll
    for (int r = 0; r < 32; r += 8)
        t[r + ty][tx] = __builtin_nontemporal_load(&S[(size_t)(k0 + r + ty) * N + n0 + tx]);
    __syncthreads();
#pragma unroll
    for (int r = 0; r < 32; r += 8)
        D[(size_t)(n0 + r + ty) * K + k0 + tx] = f2b(t[tx][r + ty]);
}

// ---------------------------------------------------------------------------
// 128x64-tile GEMM core, 8 waves (512 thr). Wave tile 32x32, acc[2][2].
// qk remainder only.
// ---------------------------------------------------------------------------
__device__ __forceinline__
void gemm64_core(const us* __restrict__ A, const us* __restrict__ Bt,
                 const float* __restrict__ bias, us* __restrict__ C,
                 int K, int ldC, int row0, int col0, us* As, us* Bs)
{
    const int tid = threadIdx.x, w = tid >> 6, lane = tid & 63;
    const int m = lane & 15, quad = lane >> 4;
    const int sr = lane >> 3;
    const int scs = (lane & 7) ^ sr;
    const int mrow0 = (w & 3) * 32, ncol0 = (w >> 2) * 32;

    f32x4_t z4 = {0.f, 0.f, 0.f, 0.f};
    f32x4_t acc[2][2] = {{z4, z4}, {z4, z4}};

    for (int k0 = 0; k0 < K; k0 += 64) {
#pragma unroll
        for (int p = 0; p < 2; p++) {
            const int r = w * 16 + p * 8 + sr;
            load16(&As[(w * 16 + p * 8) * 64], A + (size_t)(row0 + r) * K + k0 + scs * 8);
        }
        {
            const int r = w * 8 + sr;
            load16(&Bs[(w * 8) * 64], Bt + (size_t)(col0 + r) * K + k0 + scs * 8);
        }
        __syncthreads();
#pragma unroll
        for (int ks = 0; ks < 2; ks++) {
            const int slot = ((ks * 4 + quad) ^ (m & 7)) * 8;
            bf16x8_t a[2], b[2];
#pragma unroll
            for (int t = 0; t < 2; t++) {
                a[t] = *(const bf16x8_t*)&As[(mrow0 + t * 16 + m) * 64 + slot];
                b[t] = *(const bf16x8_t*)&Bs[(ncol0 + t * 16 + m) * 64 + slot];
            }
#pragma unroll
            for (int i = 0; i < 2; i++)
#pragma unroll
                for (int j = 0; j < 2; j++)
                    acc[i][j] = __builtin_amdgcn_mfma_f32_16x16x32_bf16(a[i], b[j], acc[i][j], 0, 0, 0);
        }
        __syncthreads();
    }

#pragma unroll
    for (int i = 0; i < 2; i++) {
        const int rbase = row0 + mrow0 + i * 16 + quad * 4;
#pragma unroll
        for (int j = 0; j < 2; j++) {
            const int col = col0 + ncol0 + j * 16 + m;
            const float bi = bias[col];
#pragma unroll
            for (int r = 0; r < 4; r++)
                C[(size_t)(rbase + r) * ldC + col] = f2b(acc[i][j][r] + bi);
        }
    }
}

// ---------------------------------------------------------------------------
// 128x128-tile core, 8 waves (512 thr), wave tile 64x32, acc[4][2]
// — the round-10 measured-best config. 32 KB LDS.
// ---------------------------------------------------------------------------
__device__ __forceinline__
void gemm128_core(const us* __restrict__ A, const us* __restrict__ Bt,
                  const float* __restrict__ bias, void* __restrict__ Cv,
                  int K, int ldC, int outBf16, int row0, int col0,
                  us* As, us* Bs)
{
    const int tid = threadIdx.x, w = tid >> 6, lane = tid & 63;
    const int m = lane & 15, quad = lane >> 4;
    const int sr = lane >> 3;
    const int scs = (lane & 7) ^ sr;
    const int mrow0 = (w & 1) * 64, ncol0 = (w >> 1) * 32;

    f32x4_t z = {0.f, 0.f, 0.f, 0.f};
    f32x4_t acc[4][2] = {{z,z},{z,z},{z,z},{z,z}};

    for (int k0 = 0; k0 < K; k0 += 64) {
#pragma unroll
        for (int p = 0; p < 2; p++) {
            const int r = w * 16 + p * 8 + sr;
            load16(&As[(w * 16 + p * 8) * 64], A  + (size_t)(row0 + r) * K + k0 + scs * 8);
            load16(&Bs[(w * 16 + p * 8) * 64], Bt + (size_t)(col0 + r) * K + k0 + scs * 8);
        }
        __syncthreads();
#pragma unroll
        for (int ks = 0; ks < 2; ks++) {
            const int slot = ((ks * 4 + quad) ^ (m & 7)) * 8;
            bf16x8_t a[4], b[2];
#pragma unroll
            for (int t = 0; t < 4; t++)
                a[t] = *(const bf16x8_t*)&As[(mrow0 + t * 16 + m) * 64 + slot];
#pragma unroll
            for (int t = 0; t < 2; t++)
                b[t] = *(const bf16x8_t*)&Bs[(ncol0 + t * 16 + m) * 64 + slot];
#pragma unroll
            for (int i = 0; i < 4; i++)
#pragma unroll
                for (int j = 0; j < 2; j++)
                    acc[i][j] = __builtin_amdgcn_mfma_f32_16x16x32_bf16(a[i], b[j], acc[i][j], 0, 0, 0);
        }
        __syncthreads();
    }

#pragma unroll
    for (int i = 0; i < 4; i++) {
        const int rbase = row0 + mrow0 + i * 16 + quad * 4;
        if (outBf16) {
            us* Cb = (us*)Cv;
#pragma unroll
            for (int j = 0; j < 2; j++) {
                const int col = col0 + ncol0 + j * 16 + m;
                const float bi = bias[col];
#pragma unroll
                for (int r = 0; r < 4; r++)
                    Cb[(size_t)(rbase + r) * ldC + col] = f2b(acc[i][j][r] + bi);
            }
        } else {
            float* Cb = (float*)Cv;
#pragma unroll
            for (int j = 0; j < 2; j++) {
                const int col = col0 + ncol0 + j * 16 + m;
                const float bi = bias[col];
#pragma unroll
                for (int r = 0; r < 4; r++)
                    Cb[(size_t)(rbase + r) * ldC + col] = acc[i][j][r] + bi;
            }
        }
    }
}

// ---------------------------------------------------------------------------
// Fused projections (512 threads/block), round-10 layout:
//   blocks [0,448):   v 128x128 (64 x 7)
//   blocks [448,704): q/k cols 0-255 as 128x128 (64 x 2 x {q,k})
//   blocks [704,832): q/k cols 256-319 remainder as 128x64 (64 x {q,k})
// ---------------------------------------------------------------------------
__global__ __launch_bounds__(512)
void proj_kernel(const us* __restrict__ Xq, const us* __restrict__ Xk,
                 const us* __restrict__ Xv,
                 const us* __restrict__ Wqt, const us* __restrict__ Wkt,
                 const us* __restrict__ Wvt,
                 const float* __restrict__ bq, const float* __restrict__ bk,
                 const float* __restrict__ bv,
                 us* __restrict__ qbuf, us* __restrict__ kbuf,
                 us* __restrict__ vbuf)
{
    __shared__ us As[128 * 64];
    __shared__ us Bs[128 * 64];
    const int b = blockIdx.x;
    if (b < 448) {
        gemm128_core(Xv, Wvt, bv, vbuf, D_MODEL, N_CAT, 1,
                     (b & 63) << 7, (b >> 6) << 7, As, Bs);
    } else if (b < 704) {
        const int idx = b - 448;
        const int bx = idx & 63;
        const int rest = idx >> 6;                   // 0..3
        const int cy = rest & 1, z = rest >> 1;
        gemm128_core(z ? Xk : Xq, z ? Wkt : Wqt, z ? bk : bq,
                     z ? kbuf : qbuf, D_MODEL, NQK, 1,
                     bx << 7, cy << 7, As, Bs);
    } else {
        const int idx = b - 704;
        const int bx = idx & 63;
        const int z  = idx >> 6;                     // 0,1
        gemm64_core(z ? Xk : Xq, z ? Wkt : Wqt, z ? bk : bq,
                    z ? kbuf : qbuf, D_MODEL, NQK,
                    bx << 7, 256, As, Bs);
    }
}

// out gemm: [8192][896] bf16 @ [896][1024] -> fp32 (round-10 proven config)
__global__ __launch_bounds__(512)
void gemm_out(const us* __restrict__ ab, const us* __restrict__ Wct,
              const float* __restrict__ bc, float* __restrict__ out)
{
    __shared__ us As[128 * 64];
    __shared__ us Bs[128 * 64];
    gemm128_core(ab, Wct, bc, out, N_CAT, D_MODEL, 0,
                 (int)(blockIdx.x << 7), (int)(blockIdx.y << 7), As, Bs);
}

// ---------------------------------------------------------------------------
// d=1 attention kernel (heads 0-9): MFMA scores (round-13 proven).
// ---------------------------------------------------------------------------
__global__ __launch_bounds__(256)
void attn_d1_kernel(const us* __restrict__ qb, const us* __restrict__ kb,
                    const us* __restrict__ vb,
                    const float* __restrict__ Ws, const float* __restrict__ bs,
                    us* __restrict__ ab)
{
    __shared__ us kq[96 * 64 + 64 * 64];   // Ks [96][64] | Qs [64][64]
    __shared__ float sab[64 * 36];

    us* Ks = kq;
    us* Qs = kq + 96 * 64;
    uu* vslab = (uu*)kq;                   // [95][36] aliases Ks/Qs (PV phase)

    const int tid  = threadIdx.x;
    const int wave = tid >> 6;
    const int lane = tid & 63;
    const int m    = lane & 15, quad = lane >> 4;
    const int sr   = lane >> 3;
    const int scs  = (lane & 7) ^ sr;
    const int j32  = lane & 31;
    const int half = lane >> 5;
    const int h    = blockIdx.y;           // 0..9
    const int s    = (h < 5) ? 0 : 1;
    const int ml0  = blockIdx.x * 64;
    const int l0   = ml0 & 4095;
    const int bm   = ml0 - l0;

    // ---- stage K (96 rows, window l0-16..l0+79) + Q (64 rows), swizzled ----
#pragma unroll
    for (int call = 0; call < 3; call++) {
        const int g = call * 4 + wave;       // 0..11
        const int r = g * 8 + sr;            // 0..95
        int src = l0 - 16 + r;
        src = src < 0 ? 0 : (src > 4095 ? 4095 : src);
        load16(&Ks[(g * 8) * 64], kb + (size_t)(bm + src) * NQK + s * 64 + scs * 8);
    }
#pragma unroll
    for (int call = 0; call < 2; call++) {
        const int g = call * 4 + wave;       // 0..7
        const int r = g * 8 + sr;            // 0..63
        load16(&Qs[(g * 8) * 64], qb + (size_t)(ml0 + r) * NQK + s * 64 + scs * 8);
    }

    // ---- T14: issue v loads now (drained by barrier-1) ----
    const uu4* vg4 = (const uu4*)vb;       // row stride 112 uu4
    uu4 vreg[3];
#pragma unroll
    for (int it = 0; it < 3; it++) {
        const int idx = it * 256 + tid;
        if (idx < 95 * 8) {
            const int r = idx >> 3, c4 = idx & 7;
            int src = l0 - 16 + r;
            src = src < 0 ? 0 : (src > 4095 ? 4095 : src);
            vreg[it] = vg4[(size_t)(bm + src) * 112 + h * 8 + c4];
        }
    }
    __syncthreads();

    // ---- scores via MFMA: wave p-tile p0, 3 w-tiles, K=64 (2 steps) ----
    const int p0 = wave * 16;
    f32x4_t z = {0.f, 0.f, 0.f, 0.f};
    f32x4_t accs[3] = {z, z, z};
#pragma unroll
    for (int ks = 0; ks < 2; ks++) {
        const int slot = ((ks * 4 + quad) ^ (m & 7)) * 8;
        bf16x8_t qa = *(const bf16x8_t*)&Qs[(p0 + m) * 64 + slot];
#pragma unroll
        for (int wt = 0; wt < 3; wt++) {
            bf16x8_t kb8 = *(const bf16x8_t*)&Ks[(p0 + wt * 16 + m) * 64 + slot];
            accs[wt] = __builtin_amdgcn_mfma_f32_16x16x32_bf16(qa, kb8, accs[wt], 0, 0, 0);
        }
    }
    // banded extract -> sab (C layout: row = quad*4+reg, col = m)
#pragma unroll
    for (int wt = 0; wt < 3; wt++)
#pragma unroll
        for (int r = 0; r < 4; r++) {
            const int ploc = quad * 4 + r;
            const int j = wt * 16 + m - ploc;
            if (j >= 0 && j < 32)
                sab[(p0 + ploc) * 36 + j] = accs[wt][r] * 0.125f;
        }
    __syncthreads();    // Ks/Qs reads done -> vslab overwrite safe

    // ---- v ds_writes from registers ----
#pragma unroll
    for (int it = 0; it < 3; it++) {
        const int idx = it * 256 + tid;
        if (idx < 95 * 8) {
            const int r = idx >> 3, c4 = idx & 7;
            *(uu4*)&vslab[r * 36 + c4 * 4] = vreg[it];
        }
    }
    float wsr[32];
#pragma unroll
    for (int k = 0; k < 32; k++) wsr[k] = Ws[(size_t)h * 1024 + k * 32 + j32];
    const float bsv = bs[h * 32 + j32];

    // ---- resample + softmax -> sab overwrite (wave-private rows) ----
#pragma unroll
    for (int i = 0; i < 8; i++) {
        const int p = wave * 16 + i * 2 + half;
        const float4* s4 = (const float4*)&sab[p * 36];
        float acc = bsv;
#pragma unroll
        for (int q = 0; q < 8; q++) {
            float4 v = s4[q];
            acc = fmaf(v.x, wsr[q * 4 + 0], acc);
            acc = fmaf(v.y, wsr[q * 4 + 1], acc);
            acc = fmaf(v.z, wsr[q * 4 + 2], acc);
            acc = fmaf(v.w, wsr[q * 4 + 3], acc);
        }
        float mx = acc;
#pragma unroll
        for (int off = 16; off > 0; off >>= 1) mx = fmaxf(mx, __shfl_xor(mx, off, 64));
        float ex = __expf(acc - mx);
        float sum = ex;
#pragma unroll
        for (int off = 16; off > 0; off >>= 1) sum += __shfl_xor(sum, off, 64);
        sab[p * 36 + j32] = ex / sum;
    }
    __syncthreads();   // vslab fully staged

    // ---- PV: 8 positions per pass (d=1: row base = p) ----
    const int o = lane >> 3;
    const int c = lane & 7;
#pragma unroll
    for (int pass = 0; pass < 2; pass++) {
        const int p  = wave * 16 + pass * 8 + o;
        const int ml = ml0 + p;
        float a0 = 0.f, a1 = 0.f, a2 = 0.f, a3 = 0.f;
        float a4 = 0.f, a5 = 0.f, a6 = 0.f, a7 = 0.f;
#pragma unroll
        for (int mg = 0; mg < 4; mg++) {
            const float4 wA = *(const float4*)&sab[p * 36 + mg * 8];
            const float4 wB = *(const float4*)&sab[p * 36 + mg * 8 + 4];
            const float at8[8] = {wA.x, wA.y, wA.z, wA.w, wB.x, wB.y, wB.z, wB.w};
#pragma unroll
            for (int m2 = 0; m2 < 8; m2++) {
                const float at = at8[m2];
                uu4 vd = *(const uu4*)&vslab[(p + mg * 8 + m2) * 36 + c * 4];
                a0 = fmaf(blo(vd.x), at, a0); a1 = fmaf(bhi(vd.x), at, a1);
                a2 = fmaf(blo(vd.y), at, a2); a3 = fmaf(bhi(vd.y), at, a3);
                a4 = fmaf(blo(vd.z), at, a4); a5 = fmaf(bhi(vd.z), at, a5);
                a6 = fmaf(blo(vd.w), at, a6); a7 = fmaf(bhi(vd.w), at, a7);
            }
        }
        uu4 od;
        od.x = pack2(a0, a1); od.y = pack2(a2, a3);
        od.z = pack2(a4, a5); od.w = pack2(a6, a7);
        *(uu4*)&((uu*)ab)[(size_t)ml * 448 + h * 32 + c * 4] = od;
    }
}

// ---------------------------------------------------------------------------
// Dilated attention kernel (heads 10-13, scalar path; single 512-block
// launch — splitting it regressed to 1 block/CU, round-15 lesson).
// ---------------------------------------------------------------------------
template<int ROWS>
__global__ __launch_bounds__(256)
void attn_kernel(const us* __restrict__ qb, const us* __restrict__ kb,
                 const us* __restrict__ vb,
                 const float* __restrict__ Ws, const float* __restrict__ bs,
                 us* __restrict__ ab, int hbase)
{
    __shared__ uu    kv[ROWS * 36];
    __shared__ uu    qslab[64 * 32];
    __shared__ float sab[64 * 36];

    constexpr int VT = (ROWS * 8 + 255) / 256;

    const int tid  = threadIdx.x;
    const int wave = tid >> 6;
    const int lane = tid & 63;
    const int j    = lane & 31;
    const int half = lane >> 5;
    const int h    = hbase + blockIdx.y;
    const int s    = subhead_of(h);
    const int ld   = (s <= 1) ? 0 : (s - 1);
    const int d    = 1 << ld;
    const int ml0  = blockIdx.x * 64;
    const int l0   = ml0 & 4095;
    const int bm   = ml0 - l0;
    const int W    = 64 + 31 * d;
    const int Bseg = W >> ld;

    const uu4* kg4 = (const uu4*)kb;
    const uu4* qg4 = (const uu4*)qb;
    for (int idx = tid; idx < W * 8; idx += 256) {
        int r = idx >> 3, c4 = idx & 7;
        int src = l0 - 16 * d + r;
        src = src < 0 ? 0 : (src > 4095 ? 4095 : src);
        int slot = (r & (d - 1)) * Bseg + (r >> ld);
        *(uu4*)&kv[slot * 36 + c4 * 4] = kg4[(size_t)(bm + src) * 40 + s * 8 + c4];
    }
#pragma unroll
    for (int it = 0; it < 2; it++) {
        const int idx = it * 256 + tid;
        const int r = idx >> 3, c4 = idx & 7;
        load16(&qslab[(it * 256 + wave * 64) * 4],
               &qg4[(size_t)(ml0 + r) * 40 + s * 8 + c4]);
    }

    const uu4* vg4 = (const uu4*)vb;
    uu4 vreg[VT];
#pragma unroll
    for (int it = 0; it < VT; it++) {
        const int idx = it * 256 + tid;
        if (idx < W * 8) {
            const int r = idx >> 3, c4 = idx & 7;
            int src = l0 - 16 * d + r;
            src = src < 0 ? 0 : (src > 4095 ? 4095 : src);
            vreg[it] = vg4[(size_t)(bm + src) * 112 + h * 8 + c4];
        }
    }
    __syncthreads();

#pragma unroll
    for (int i = 0; i < 8; i++) {
        const int p = wave * 16 + i * 2 + half;
        const int sb = (p & (d - 1)) * Bseg + (p >> ld);
        const uu4* k4 = (const uu4*)&kv[(sb + j) * 36];
        const uu4* q4 = (const uu4*)&qslab[p * 32];
        float acc = 0.f;
#pragma unroll
        for (int q = 0; q < 8; q++) {
            uu4 kd = k4[q];
            uu4 qd = q4[q];
            acc = fmaf(blo(kd.x), blo(qd.x), acc); acc = fmaf(bhi(kd.x), bhi(qd.x), acc);
            acc = fmaf(blo(kd.y), blo(qd.y), acc); acc = fmaf(bhi(kd.y), bhi(qd.y), acc);
            acc = fmaf(blo(kd.z), blo(qd.z), acc); acc = fmaf(bhi(kd.z), bhi(qd.z), acc);
            acc = fmaf(blo(kd.w), blo(qd.w), acc); acc = fmaf(bhi(kd.w), bhi(qd.w), acc);
        }
        sab[p * 36 + j] = acc * 0.125f;
    }
    __syncthreads();

#pragma unroll
    for (int it = 0; it < VT; it++) {
        const int idx = it * 256 + tid;
        if (idx < W * 8) {
            const int r = idx >> 3, c4 = idx & 7;
            const int slot = (r & (d - 1)) * Bseg + (r >> ld);
            *(uu4*)&kv[slot * 36 + c4 * 4] = vreg[it];
        }
    }
    float wsr[32];
#pragma unroll
    for (int k = 0; k < 32; k++) wsr[k] = Ws[(size_t)h * 1024 + k * 32 + j];
    const float bsv = bs[h * 32 + j];

#pragma unroll
    for (int i = 0; i < 8; i++) {
        const int p = wave * 16 + i * 2 + half;
        const float4* s4 = (const float4*)&sab[p * 36];
        float acc = bsv;
#pragma unroll
        for (int q = 0; q < 8; q++) {
            float4 v = s4[q];
            acc = fmaf(v.x, wsr[q * 4 + 0], acc);
            acc = fmaf(v.y, wsr[q * 4 + 1], acc);
            acc = fmaf(v.z, wsr[q * 4 + 2], acc);
            acc = fmaf(v.w, wsr[q * 4 + 3], acc);
        }
        float mx = acc;
#pragma unroll
        for (int off = 16; off > 0; off >>= 1) mx = fmaxf(mx, __shfl_xor(mx, off, 64));
        float ex = __expf(acc - mx);
        float sum = ex;
#pragma unroll
        for (int off = 16; off > 0; off >>= 1) sum += __shfl_xor(sum, off, 64);
        sab[p * 36 + j] = ex / sum;
    }
    __syncthreads();

    const int o = lane >> 3;
    const int c = lane & 7;
#pragma unroll
    for (int pass = 0; pass < 2; pass++) {
        const int p  = wave * 16 + pass * 8 + o;
        const int ml = ml0 + p;
        const int sbp = (p & (d - 1)) * Bseg + (p >> ld);
        float a0 = 0.f, a1 = 0.f, a2 = 0.f, a3 = 0.f;
        float a4 = 0.f, a5 = 0.f, a6 = 0.f, a7 = 0.f;
#pragma unroll
        for (int mg = 0; mg < 4; mg++) {
            const float4 wA = *(const float4*)&sab[p * 36 + mg * 8];
            const float4 wB = *(const float4*)&sab[p * 36 + mg * 8 + 4];
            const float at8[8] = {wA.x, wA.y, wA.z, wA.w, wB.x, wB.y, wB.z, wB.w};
#pragma unroll
            for (int m2 = 0; m2 < 8; m2++) {
                const float at = at8[m2];
                uu4 vd = *(const uu4*)&kv[(sbp + mg * 8 + m2) * 36 + c * 4];
                a0 = fmaf(blo(vd.x), at, a0); a1 = fmaf(bhi(vd.x), at, a1);
                a2 = fmaf(blo(vd.y), at, a2); a3 = fmaf(bhi(vd.y), at, a3);
                a4 = fmaf(blo(vd.z), at, a4); a5 = fmaf(bhi(vd.z), at, a5);
                a6 = fmaf(blo(vd.w), at, a6); a7 = fmaf(bhi(vd.w), at, a7);
            }
        }
        uu4 od;
        od.x = pack2(a0, a1); od.y = pack2(a2, a3);
        od.z = pack2(a4, a5); od.w = pack2(a6, a7);
        *(uu4*)&((uu*)ab)[(size_t)ml * 448 + h * 32 + c * 4] = od;
    }
}

// ---------------------------------------------------------------------------
extern "C" void kernel_launch(void* const* d_in, const int* in_sizes, int n_in,
                              void* d_out, int out_size, void* d_ws, size_t ws_size,
                              hipStream_t stream)
{
    const float* query = (const float*)d_in[0];
    const float* key   = (const float*)d_in[1];
    const float* value = (const float*)d_in[2];
    const float* Wq    = (const float*)d_in[3];
    const float* bq    = (const float*)d_in[4];
    const float* Wk    = (const float*)d_in[5];
    const float* bk    = (const float*)d_in[6];
    const float* Wv    = (const float*)d_in[7];
    const float* bv    = (const float*)d_in[8];
    const float* Ws    = (const float*)d_in[9];
    const float* bs    = (const float*)d_in[10];
    const float* Wc    = (const float*)d_in[11];
    const float* bc    = (const float*)d_in[12];
    float* out = (float*)d_out;

    // workspace carve (bf16 elements). ab aliases Xq (Xq dead after q gemm).
    us* w = (us*)d_ws;
    us* Xq  = w;                          // 8192*1024
    us* ab  = w;                          // 8192*896 (alias of Xq)
    us* Xk  = Xq  + (size_t)M_ROWS * D_MODEL;
    us* Xv  = Xk  + (size_t)M_ROWS * D_MODEL;
    us* Wqt = Xv  + (size_t)M_ROWS * D_MODEL;           // [320][1024]
    us* Wkt = Wqt + (size_t)SUBHEADS * D_INT * D_MODEL;
    us* Wvt = Wkt + (size_t)SUBHEADS * D_INT * D_MODEL; // [896][1024]
    us* Wct = Wvt + (size_t)HEADS * D_INT * D_MODEL;    // [1024][896]
    us* qbuf = Wct + (size_t)D_MODEL * N_CAT;           // [8192][320]
    us* kbuf = qbuf + (size_t)M_ROWS * NQK;
    us* vbuf = kbuf + (size_t)M_ROWS * NQK;             // [8192][896]

    dim3 blk(256);
    dim3 blk512(512);

    // prep: ILP-forced q/k/v casts + weight transposes in one launch
    prep_kernel<<<dim3(CAST_BLK + 2432), blk, 0, stream>>>(
        query, key, value,
        Wq, Wk, Wv, Wc, Xq, Xk, Xv, Wqt, Wkt, Wvt, Wct);

    // fused q/k/v projections: 448 v-128 + 256 qk-128 + 128 qk-64 = 832
    proj_kernel<<<dim3(832), blk512, 0, stream>>>(
        Xq, Xk, Xv, Wqt, Wkt, Wvt, bq, bk, bv, qbuf, kbuf, vbuf);

    // attention:
    //   heads 0-9 (d=1): MFMA-scores kernel, grid 1280, 29.7 KB -> 5/CU
    //   heads 10-13 (d>=2): scalar path, single 512-block launch
    attn_d1_kernel<<<dim3(M_ROWS / 64, 10), blk, 0, stream>>>(
        qbuf, kbuf, vbuf, Ws, bs, ab);
    attn_kernel<312><<<dim3(M_ROWS / 64, 4), blk, 0, stream>>>(
        qbuf, kbuf, vbuf, Ws, bs, ab, 10);

    // out gemm: [8192][896] @ [896][1024] -> fp32 (round-10 config)
    gemm_out<<<dim3(M_ROWS / 128, D_MODEL / 128), blk512, 0, stream>>>(
        ab, Wct, bc, out);
}